// Round 5
// baseline (94.126 us; speedup 1.0000x reference)
//
#include <hip/hip_runtime.h>
#include <cstdint>
#include <cstddef>

#define HF 128   // hidden feature dim
#define NTY 8    // edge types

typedef __attribute__((ext_vector_type(8))) short short8;     // 8 bf16
typedef __attribute__((ext_vector_type(8))) _Float16 half8;   // 8 fp16
typedef __attribute__((ext_vector_type(4))) float f32x4;
typedef unsigned int u32;
typedef unsigned short u16;

__device__ __forceinline__ short f2bf(float x) {   // RNE float->bf16
  union { float f; unsigned u; } v; v.f = x;
  unsigned r = v.u + 0x7FFFu + ((v.u >> 16) & 1u);
  return (short)(r >> 16);
}
__device__ __forceinline__ u16 f2h(float x) {      // RNE float->fp16 bits
  union { _Float16 h; u16 u; } v; v.h = (_Float16)x; return v.u;
}
__device__ __forceinline__ float asf(u32 u) {
  union { u32 x; float f; } v; v.x = u; return v.f;
}
// packed bf16 convert: low16 = bf16(a), high16 = bf16(b)
__device__ __forceinline__ u32 cvtpk_bf16(float a, float b) {
  u32 r;
  asm("v_cvt_pk_bf16_f32 %0, %1, %2" : "=v"(r) : "v"(a), "v"(b));
  return r;
}
// packed fp16: relu(p + q) on 2x16b at once
__device__ __forceinline__ u32 pk_addrelu_f16(u32 p, u32 q) {
  u32 r;
  asm("v_pk_add_f16 %0, %1, %2" : "=v"(r) : "v"(p), "v"(q));
  asm("v_pk_max_f16 %0, %1, 0"  : "=v"(r) : "v"(r));
  return r;
}

// ---------------------------------------------------------------------------
// Prep: Wbf[j][k] = bf16( W1[j&127][ ((j>>7)<<7) + k ] ), j=0..255, k=0..127
// ---------------------------------------------------------------------------
__global__ __launch_bounds__(256) void prep_w(
    const float* __restrict__ W1, u16* __restrict__ Wbf)
{
  const int id = blockIdx.x * 256 + threadIdx.x;   // 0..4095
  const int j = id >> 4, c = id & 15;              // c: 8-float chunk
  const float* src = W1 + (size_t)(j & 127) * 256 + ((j >> 7) << 7) + 8 * c;
  const float4 x = *(const float4*)src;
  const float4 y = *(const float4*)(src + 4);
  short8 b;
  b[0]=f2bf(x.x); b[1]=f2bf(x.y); b[2]=f2bf(x.z); b[3]=f2bf(x.w);
  b[4]=f2bf(y.x); b[5]=f2bf(y.y); b[6]=f2bf(y.z); b[7]=f2bf(y.w);
  *(short8*)(&Wbf[(size_t)j * HF + 8 * c]) = b;
}

// ---------------------------------------------------------------------------
// Kernel A v2 (barrier-free, LDS-free):
//   PQ[n][j] = fp16( (j<128) ? h[n]@W1a.T + b1 : h[n]@W1b.T )
//   Block = 512 thr = 8 waves: wave(ws,wq) = nodes [tile*32+16ws, +16) x cols
//   [64wq, +64). A-operand = Wbf frags (direct 16B loads, L2-hit);
//   B-operand = h row split hi+lo bf16 in-register (2 MFMA passes).
//   C: per lane 4 consecutive j for ONE node -> packed 8B fp16 stores.
// ---------------------------------------------------------------------------
__global__ __launch_bounds__(512) void node_pq_v2(
    const float* __restrict__ h, const u16* __restrict__ Wbf,
    const float* __restrict__ b1, u16* __restrict__ PQ, int n_nodes)
{
  const int t    = threadIdx.x;
  const int lane = t & 63;
  const int wid  = t >> 6;
  const int wq   = wid & 3;          // col quarter (64 cols)
  const int wsb  = wid >> 2;         // node half (16 nodes)
  const int cl   = lane & 15;
  const int kg   = lane >> 4;
  const int nodeR = blockIdx.x * 32 + 16 * wsb + cl;
  const int node  = (nodeR < n_nodes) ? nodeR : (n_nodes - 1);

  // ---- B operand: h[node] -> hi/lo bf16 fragments (k = 32ks + 8kg + i) ----
  const float* hp = h + (size_t)node * HF;
  short8 bh[4], bl[4];
#pragma unroll
  for (int ks = 0; ks < 4; ++ks) {
    const float4 x = *(const float4*)(hp + 32 * ks + 8 * kg);
    const float4 y = *(const float4*)(hp + 32 * ks + 8 * kg + 4);
    const float f[8] = {x.x, x.y, x.z, x.w, y.x, y.y, y.z, y.w};
    union { u32 w[4]; short8 v; } H, L;
#pragma unroll
    for (int p = 0; p < 4; ++p) {
      const float a = f[2 * p], b = f[2 * p + 1];
      const u32 hb = cvtpk_bf16(a, b);
      const float ea = a - asf(hb << 16);
      const float eb = b - asf(hb & 0xFFFF0000u);
      H.w[p] = hb;
      L.w[p] = cvtpk_bf16(ea, eb);
    }
    bh[ks] = H.v;
    bl[ks] = L.v;
  }

  // ---- per j-tile: A frags from Wbf, 8 MFMAs, pack fp16, 8B store ----
#pragma unroll
  for (int mi = 0; mi < 4; ++mi) {
    const int j0 = 64 * wq + 16 * mi;          // j-tile base
    f32x4 acc;
    if (wq < 2) {                              // j < 128: bias
      const float4 bv = *(const float4*)(b1 + j0 + 4 * kg);
      acc = f32x4{bv.x, bv.y, bv.z, bv.w};
    } else {
      acc = f32x4{0.0f, 0.0f, 0.0f, 0.0f};
    }
#pragma unroll
    for (int ks = 0; ks < 4; ++ks) {
      const short8 af = *(const short8*)(Wbf + (size_t)(j0 + cl) * HF + 32 * ks + 8 * kg);
      acc = __builtin_amdgcn_mfma_f32_16x16x32_bf16(af, bh[ks], acc, 0, 0, 0);
      acc = __builtin_amdgcn_mfma_f32_16x16x32_bf16(af, bl[ks], acc, 0, 0, 0);
    }
    if (nodeR < n_nodes) {
      uint2 o;
      o.x = (u32)f2h(acc[0]) | ((u32)f2h(acc[1]) << 16);
      o.y = (u32)f2h(acc[2]) | ((u32)f2h(acc[3]) << 16);
      *(uint2*)(&PQ[(size_t)nodeR * 256 + j0 + 4 * kg]) = o;
    }
  }
}

// ---------------------------------------------------------------------------
// Kernel B (MFMA): 16 edges per wave-tile.  (unchanged from round 4)
// ---------------------------------------------------------------------------
__global__ __launch_bounds__(256) void edge_mlp_mfma(
    const u16* __restrict__ PQ, const int* __restrict__ src,
    const int* __restrict__ dst, const float* __restrict__ W2,
    const float* __restrict__ b2, float* __restrict__ out, int n_edges)
{
  const int t    = threadIdx.x;
  const int lane = t & 63;
  const int cl   = lane & 15;
  const int kg   = lane >> 4;

  // B fragments: bf[ks][i] = W2[cl][32ks+8kg+i] (fp16), 0 for cl>=8
  half8 bf[4];
#pragma unroll
  for (int ks = 0; ks < 4; ++ks) {
    if (cl < NTY) {
      const float* wp = W2 + cl * HF + 32 * ks + 8 * kg;
      const float4 x = *(const float4*)wp;
      const float4 y = *(const float4*)(wp + 4);
      bf[ks][0]=(_Float16)x.x; bf[ks][1]=(_Float16)x.y;
      bf[ks][2]=(_Float16)x.z; bf[ks][3]=(_Float16)x.w;
      bf[ks][4]=(_Float16)y.x; bf[ks][5]=(_Float16)y.y;
      bf[ks][6]=(_Float16)y.z; bf[ks][7]=(_Float16)y.w;
    } else {
#pragma unroll
      for (int i = 0; i < 8; ++i) bf[ks][i] = (_Float16)0.0f;
    }
  }
  const float bbias = (cl < NTY) ? b2[cl] : 0.0f;

  const int gw = blockIdx.x * 4 + (t >> 6);   // global wave id
  const int nw = gridDim.x * 4;

  for (int base = gw * 16; base < n_edges; base += nw * 16) {
    int e = base + cl;
    if (e >= n_edges) e = n_edges - 1;
    const int s = src[e];
    const int d = dst[e];
    const u16* pr = PQ + (size_t)s * 256 + 8 * kg;        // P half-row chunk
    const u16* qr = PQ + (size_t)d * 256 + HF + 8 * kg;   // Q half-row chunk

    uint4 P[4], Q[4];
#pragma unroll
    for (int ks = 0; ks < 4; ++ks) P[ks] = *(const uint4*)(pr + 32 * ks);
#pragma unroll
    for (int ks = 0; ks < 4; ++ks) Q[ks] = *(const uint4*)(qr + 32 * ks);

    f32x4 acc = f32x4{0.0f, 0.0f, 0.0f, 0.0f};
#pragma unroll
    for (int ks = 0; ks < 4; ++ks) {
      union { u32 w[4]; half8 v; } a;
      a.w[0] = pk_addrelu_f16(P[ks].x, Q[ks].x);
      a.w[1] = pk_addrelu_f16(P[ks].y, Q[ks].y);
      a.w[2] = pk_addrelu_f16(P[ks].z, Q[ks].z);
      a.w[3] = pk_addrelu_f16(P[ks].w, Q[ks].w);
      acc = __builtin_amdgcn_mfma_f32_16x16x32_f16(a.v, bf[ks], acc, 0, 0, 0);
    }

    // per-reg softmax over the 8 types (lanes cl 0..7; 8..15 are zero-pad)
    float val[4];
#pragma unroll
    for (int r = 0; r < 4; ++r) {
      const float L = acc[r] + bbias;
      float m = fmaxf(L, __shfl_xor(L, 1, 64));
      m = fmaxf(m, __shfl_xor(m, 2, 64));
      m = fmaxf(m, __shfl_xor(m, 4, 64));
      const float ex = __expf(L - m);
      float sm = ex + __shfl_xor(ex, 1, 64);
      sm += __shfl_xor(sm, 2, 64);
      sm += __shfl_xor(sm, 4, 64);
      val[r] = ex / sm;
    }

    if (cl < NTY) {
#pragma unroll
      for (int r = 0; r < 4; ++r) {
        const int ee = base + 4 * kg + r;
        if (ee < n_edges) out[(size_t)ee * NTY + cl] = val[r];
      }
    }
  }
}

// ---------------------------------------------------------------------------
extern "C" void kernel_launch(void* const* d_in, const int* in_sizes, int n_in,
                              void* d_out, int out_size, void* d_ws, size_t ws_size,
                              hipStream_t stream) {
  const float* h   = (const float*)d_in[0];
  const int*   src = (const int*)d_in[1];
  const int*   dst = (const int*)d_in[2];
  const float* W1  = (const float*)d_in[3];
  const float* b1  = (const float*)d_in[4];
  const float* W2  = (const float*)d_in[5];
  const float* b2  = (const float*)d_in[6];
  float* out = (float*)d_out;

  const int n_nodes = in_sizes[0] / HF;   // 50000
  const int n_edges = in_sizes[1];        // 500000
  u16* PQ  = (u16*)d_ws;                  // [n_nodes][256] fp16 = 25.6 MB
  u16* Wbf = PQ + (size_t)n_nodes * 256;  // [256][128] bf16 = 64 KB

  hipLaunchKernelGGL(prep_w, dim3(16), dim3(256), 0, stream, W1, Wbf);
  hipLaunchKernelGGL(node_pq_v2, dim3((n_nodes + 31) / 32), dim3(512), 0, stream,
                     h, Wbf, b1, PQ, n_nodes);
  hipLaunchKernelGGL(edge_mlp_mfma, dim3(2048), dim3(256), 0, stream,
                     PQ, src, dst, W2, b2, out, n_edges);
}

// Round 6
// 90.570 us; speedup vs baseline: 1.0393x; 1.0393x over previous
//
#include <hip/hip_runtime.h>
#include <cstdint>
#include <cstddef>

#define HF 128   // hidden feature dim
#define NTY 8    // edge types

typedef __attribute__((ext_vector_type(8))) short short8;     // 8 bf16
typedef __attribute__((ext_vector_type(8))) _Float16 half8;   // 8 fp16
typedef __attribute__((ext_vector_type(4))) float f32x4;
typedef unsigned int u32;
typedef unsigned short u16;

__device__ __forceinline__ short f2bf(float x) {   // RNE float->bf16
  union { float f; unsigned u; } v; v.f = x;
  unsigned r = v.u + 0x7FFFu + ((v.u >> 16) & 1u);
  return (short)(r >> 16);
}
__device__ __forceinline__ u16 f2h(float x) {      // RNE float->fp16 bits
  union { _Float16 h; u16 u; } v; v.h = (_Float16)x; return v.u;
}
__device__ __forceinline__ float asf(u32 u) {
  union { u32 x; float f; } v; v.x = u; return v.f;
}
// packed bf16 convert: low16 = bf16(a), high16 = bf16(b)
__device__ __forceinline__ u32 cvtpk_bf16(float a, float b) {
  u32 r;
  asm("v_cvt_pk_bf16_f32 %0, %1, %2" : "=v"(r) : "v"(a), "v"(b));
  return r;
}
// packed fp16: relu(p + q) on 2x16b at once
__device__ __forceinline__ u32 pk_addrelu_f16(u32 p, u32 q) {
  u32 r;
  asm("v_pk_add_f16 %0, %1, %2" : "=v"(r) : "v"(p), "v"(q));
  asm("v_pk_max_f16 %0, %1, 0"  : "=v"(r) : "v"(r));
  return r;
}

// ---------------------------------------------------------------------------
// Prep: Wbf[j][k] = bf16( W1[j&127][ ((j>>7)<<7) + k ] ), j=0..255, k=0..127
// ---------------------------------------------------------------------------
__global__ __launch_bounds__(256) void prep_w(
    const float* __restrict__ W1, u16* __restrict__ Wbf)
{
  const int id = blockIdx.x * 256 + threadIdx.x;   // 0..4095
  const int j = id >> 4, c = id & 15;              // c: 8-float chunk
  const float* src = W1 + (size_t)(j & 127) * 256 + ((j >> 7) << 7) + 8 * c;
  const float4 x = *(const float4*)src;
  const float4 y = *(const float4*)(src + 4);
  short8 b;
  b[0]=f2bf(x.x); b[1]=f2bf(x.y); b[2]=f2bf(x.z); b[3]=f2bf(x.w);
  b[4]=f2bf(y.x); b[5]=f2bf(y.y); b[6]=f2bf(y.z); b[7]=f2bf(y.w);
  *(short8*)(&Wbf[(size_t)j * HF + 8 * c]) = b;
}

// ---------------------------------------------------------------------------
// Kernel A v3 (barrier-free, LDS-free, wave-autonomous):
//   PQ[n][j] = fp16( (j<128) ? h[n]@W1a.T + b1 : h[n]@W1b.T )
//   Each WAVE owns one 16-node tile across ALL 256 cols:
//     B-operand = h rows (lane cl = node) split hi+lo bf16 in-register;
//     A-operand = Wbf row-fragments (direct 16B loads, L2-resident);
//     16 j-tiles x 8 chained MFMA = 128 MFMA/wave (16 independent chains).
//   Bias added AFTER the chain (hoisted to regs; off the critical path).
//   C: lane holds 4 consecutive j for ONE node -> packed 8B fp16 stores.
// ---------------------------------------------------------------------------
__global__ __launch_bounds__(256) void node_pq_v3(
    const float* __restrict__ h, const u16* __restrict__ Wbf,
    const float* __restrict__ b1, u16* __restrict__ PQ, int n_nodes)
{
  const int t    = threadIdx.x;
  const int lane = t & 63;
  const int cl   = lane & 15;          // node-in-tile  (B col / C col)
  const int kg   = lane >> 4;          // k-group       (C rows 4kg..4kg+3)

  // bias regs: bias4[jt] = b1[16*jt + 4*kg .. +3]  (j<128 tiles only)
  float4 bias4[8];
#pragma unroll
  for (int jt = 0; jt < 8; ++jt)
    bias4[jt] = *(const float4*)(b1 + 16 * jt + 4 * kg);

  const int gw = blockIdx.x * 4 + (t >> 6);   // global wave id
  const int nw = gridDim.x * 4;
  const int n_tiles = (n_nodes + 15) >> 4;

  for (int wt = gw; wt < n_tiles; wt += nw) {
    const int nodeR = wt * 16 + cl;
    const int node  = (nodeR < n_nodes) ? nodeR : (n_nodes - 1);

    // ---- B operand: h[node] -> hi/lo bf16 frags (k = 32ks + 8kg + i) ----
    const float* hp = h + (size_t)node * HF;
    short8 bh[4], bl[4];
#pragma unroll
    for (int ks = 0; ks < 4; ++ks) {
      const float4 x = *(const float4*)(hp + 32 * ks + 8 * kg);
      const float4 y = *(const float4*)(hp + 32 * ks + 8 * kg + 4);
      const float f[8] = {x.x, x.y, x.z, x.w, y.x, y.y, y.z, y.w};
      union { u32 w[4]; short8 v; } H, L;
#pragma unroll
      for (int p = 0; p < 4; ++p) {
        const float a = f[2 * p], b = f[2 * p + 1];
        const u32 hb = cvtpk_bf16(a, b);
        const float ea = a - asf(hb << 16);
        const float eb = b - asf(hb & 0xFFFF0000u);
        H.w[p] = hb;
        L.w[p] = cvtpk_bf16(ea, eb);
      }
      bh[ks] = H.v;
      bl[ks] = L.v;
    }

    // ---- 16 j-tiles: 4 Wbf frag loads + 8 chained MFMA + 8B store ----
#pragma unroll
    for (int jt = 0; jt < 16; ++jt) {
      const int j0 = 16 * jt;
      f32x4 acc = f32x4{0.0f, 0.0f, 0.0f, 0.0f};
#pragma unroll
      for (int ks = 0; ks < 4; ++ks) {
        const short8 af = *(const short8*)(Wbf + (size_t)(j0 + cl) * HF + 32 * ks + 8 * kg);
        acc = __builtin_amdgcn_mfma_f32_16x16x32_bf16(af, bh[ks], acc, 0, 0, 0);
        acc = __builtin_amdgcn_mfma_f32_16x16x32_bf16(af, bl[ks], acc, 0, 0, 0);
      }
      if (jt < 8) {   // bias after the chain (same sum, off critical path)
        acc[0] += bias4[jt].x; acc[1] += bias4[jt].y;
        acc[2] += bias4[jt].z; acc[3] += bias4[jt].w;
      }
      if (nodeR < n_nodes) {
        uint2 o;
        o.x = (u32)f2h(acc[0]) | ((u32)f2h(acc[1]) << 16);
        o.y = (u32)f2h(acc[2]) | ((u32)f2h(acc[3]) << 16);
        *(uint2*)(&PQ[(size_t)nodeR * 256 + j0 + 4 * kg]) = o;
      }
    }
  }
}

// ---------------------------------------------------------------------------
// Kernel B (MFMA): 16 edges per wave-tile.  (unchanged — proven 44 us)
// ---------------------------------------------------------------------------
__global__ __launch_bounds__(256) void edge_mlp_mfma(
    const u16* __restrict__ PQ, const int* __restrict__ src,
    const int* __restrict__ dst, const float* __restrict__ W2,
    const float* __restrict__ b2, float* __restrict__ out, int n_edges)
{
  const int t    = threadIdx.x;
  const int lane = t & 63;
  const int cl   = lane & 15;
  const int kg   = lane >> 4;

  // B fragments: bf[ks][i] = W2[cl][32ks+8kg+i] (fp16), 0 for cl>=8
  half8 bf[4];
#pragma unroll
  for (int ks = 0; ks < 4; ++ks) {
    if (cl < NTY) {
      const float* wp = W2 + cl * HF + 32 * ks + 8 * kg;
      const float4 x = *(const float4*)wp;
      const float4 y = *(const float4*)(wp + 4);
      bf[ks][0]=(_Float16)x.x; bf[ks][1]=(_Float16)x.y;
      bf[ks][2]=(_Float16)x.z; bf[ks][3]=(_Float16)x.w;
      bf[ks][4]=(_Float16)y.x; bf[ks][5]=(_Float16)y.y;
      bf[ks][6]=(_Float16)y.z; bf[ks][7]=(_Float16)y.w;
    } else {
#pragma unroll
      for (int i = 0; i < 8; ++i) bf[ks][i] = (_Float16)0.0f;
    }
  }
  const float bbias = (cl < NTY) ? b2[cl] : 0.0f;

  const int gw = blockIdx.x * 4 + (t >> 6);   // global wave id
  const int nw = gridDim.x * 4;

  for (int base = gw * 16; base < n_edges; base += nw * 16) {
    int e = base + cl;
    if (e >= n_edges) e = n_edges - 1;
    const int s = src[e];
    const int d = dst[e];
    const u16* pr = PQ + (size_t)s * 256 + 8 * kg;        // P half-row chunk
    const u16* qr = PQ + (size_t)d * 256 + HF + 8 * kg;   // Q half-row chunk

    uint4 P[4], Q[4];
#pragma unroll
    for (int ks = 0; ks < 4; ++ks) P[ks] = *(const uint4*)(pr + 32 * ks);
#pragma unroll
    for (int ks = 0; ks < 4; ++ks) Q[ks] = *(const uint4*)(qr + 32 * ks);

    f32x4 acc = f32x4{0.0f, 0.0f, 0.0f, 0.0f};
#pragma unroll
    for (int ks = 0; ks < 4; ++ks) {
      union { u32 w[4]; half8 v; } a;
      a.w[0] = pk_addrelu_f16(P[ks].x, Q[ks].x);
      a.w[1] = pk_addrelu_f16(P[ks].y, Q[ks].y);
      a.w[2] = pk_addrelu_f16(P[ks].z, Q[ks].z);
      a.w[3] = pk_addrelu_f16(P[ks].w, Q[ks].w);
      acc = __builtin_amdgcn_mfma_f32_16x16x32_f16(a.v, bf[ks], acc, 0, 0, 0);
    }

    // per-reg softmax over the 8 types (lanes cl 0..7; 8..15 are zero-pad)
    float val[4];
#pragma unroll
    for (int r = 0; r < 4; ++r) {
      const float L = acc[r] + bbias;
      float m = fmaxf(L, __shfl_xor(L, 1, 64));
      m = fmaxf(m, __shfl_xor(m, 2, 64));
      m = fmaxf(m, __shfl_xor(m, 4, 64));
      const float ex = __expf(L - m);
      float sm = ex + __shfl_xor(ex, 1, 64);
      sm += __shfl_xor(sm, 2, 64);
      sm += __shfl_xor(sm, 4, 64);
      val[r] = ex / sm;
    }

    if (cl < NTY) {
#pragma unroll
      for (int r = 0; r < 4; ++r) {
        const int ee = base + 4 * kg + r;
        if (ee < n_edges) out[(size_t)ee * NTY + cl] = val[r];
      }
    }
  }
}

// ---------------------------------------------------------------------------
extern "C" void kernel_launch(void* const* d_in, const int* in_sizes, int n_in,
                              void* d_out, int out_size, void* d_ws, size_t ws_size,
                              hipStream_t stream) {
  const float* h   = (const float*)d_in[0];
  const int*   src = (const int*)d_in[1];
  const int*   dst = (const int*)d_in[2];
  const float* W1  = (const float*)d_in[3];
  const float* b1  = (const float*)d_in[4];
  const float* W2  = (const float*)d_in[5];
  const float* b2  = (const float*)d_in[6];
  float* out = (float*)d_out;

  const int n_nodes = in_sizes[0] / HF;   // 50000
  const int n_edges = in_sizes[1];        // 500000
  u16* PQ  = (u16*)d_ws;                  // [n_nodes][256] fp16 = 25.6 MB
  u16* Wbf = PQ + (size_t)n_nodes * 256;  // [256][128] bf16 = 64 KB

  const int n_tiles = (n_nodes + 15) >> 4;          // 3125
  const int nblk    = (n_tiles + 3) / 4;            // 782 (4 waves/block)

  hipLaunchKernelGGL(prep_w, dim3(16), dim3(256), 0, stream, W1, Wbf);
  hipLaunchKernelGGL(node_pq_v3, dim3(nblk), dim3(256), 0, stream,
                     h, Wbf, b1, PQ, n_nodes);
  hipLaunchKernelGGL(edge_mlp_mfma, dim3(2048), dim3(256), 0, stream,
                     PQ, src, dst, W2, b2, out, n_edges);
}

// Round 7
// 68.586 us; speedup vs baseline: 1.3724x; 1.3205x over previous
//
#include <hip/hip_runtime.h>
#include <cstdint>
#include <cstddef>

#define HF 128   // hidden feature dim
#define NTY 8    // edge types

typedef __attribute__((ext_vector_type(8))) short short8;     // 8 bf16
typedef __attribute__((ext_vector_type(8))) _Float16 half8;   // 8 fp16
typedef __attribute__((ext_vector_type(4))) float f32x4;
typedef unsigned int u32;
typedef unsigned short u16;

__device__ __forceinline__ short f2bf(float x) {   // RNE float->bf16
  union { float f; unsigned u; } v; v.f = x;
  unsigned r = v.u + 0x7FFFu + ((v.u >> 16) & 1u);
  return (short)(r >> 16);
}
__device__ __forceinline__ u16 f2h(float x) {      // RNE float->fp16 bits
  union { _Float16 h; u16 u; } v; v.h = (_Float16)x; return v.u;
}
__device__ __forceinline__ float asf(u32 u) {
  union { u32 x; float f; } v; v.x = u; return v.f;
}
// packed bf16 convert: low16 = bf16(a), high16 = bf16(b)
__device__ __forceinline__ u32 cvtpk_bf16(float a, float b) {
  u32 r;
  asm("v_cvt_pk_bf16_f32 %0, %1, %2" : "=v"(r) : "v"(a), "v"(b));
  return r;
}
// packed fp16: relu(p + q) on 2x16b at once
__device__ __forceinline__ u32 pk_addrelu_f16(u32 p, u32 q) {
  u32 r;
  asm("v_pk_add_f16 %0, %1, %2" : "=v"(r) : "v"(p), "v"(q));
  asm("v_pk_max_f16 %0, %1, 0"  : "=v"(r) : "v"(r));
  return r;
}
// global -> LDS direct copy, 16B/lane (wave-uniform LDS base + lane*16)
__device__ __forceinline__ void gload_lds16(const float* g, float* l) {
  __builtin_amdgcn_global_load_lds(
      (const __attribute__((address_space(1))) void*)g,
      (__attribute__((address_space(3))) void*)l, 16, 0, 0);
}

// ---------------------------------------------------------------------------
// Prep: Wbf[j][k] = bf16( W1[j&127][ ((j>>7)<<7) + k ] ), j=0..255, k=0..127
// ---------------------------------------------------------------------------
__global__ __launch_bounds__(256) void prep_w(
    const float* __restrict__ W1, u16* __restrict__ Wbf)
{
  const int id = blockIdx.x * 256 + threadIdx.x;   // 0..4095
  const int j = id >> 4, c = id & 15;              // c: 8-float chunk
  const float* src = W1 + (size_t)(j & 127) * 256 + ((j >> 7) << 7) + 8 * c;
  const float4 x = *(const float4*)src;
  const float4 y = *(const float4*)(src + 4);
  short8 b;
  b[0]=f2bf(x.x); b[1]=f2bf(x.y); b[2]=f2bf(x.z); b[3]=f2bf(x.w);
  b[4]=f2bf(y.x); b[5]=f2bf(y.y); b[6]=f2bf(y.z); b[7]=f2bf(y.w);
  *(short8*)(&Wbf[(size_t)j * HF + 8 * c]) = b;
}

// ---------------------------------------------------------------------------
// Kernel A v4: PQ[n][j] = fp16( (j<128) ? h[n]@W1a.T + b1 : h[n]@W1b.T )
//   Block = 256 thr = 4 waves; wave wq owns cols [64wq, 64wq+64) with its
//   W fragments RESIDENT IN REGISTERS (64 VGPR, loaded once per block).
//   Per 16-node tile: h staged coalesced into LDS (global_load_lds w16,
//   double-buffered, chunk-XOR swizzle on source+read, linear dest),
//   per-lane hi/lo bf16 split in-register, 32 MFMA/wave, packed 8B stores.
//   One barrier per tile; grid-stride over 3125 tiles.
// ---------------------------------------------------------------------------
__global__ __launch_bounds__(256) void node_pq_v4(
    const float* __restrict__ h, const u16* __restrict__ Wbf,
    const float* __restrict__ b1, u16* __restrict__ PQ,
    int n_nodes, int n_tiles)
{
  __shared__ float Hs[2][16 * HF];     // 2 x 8 KB
  const int t    = threadIdx.x;
  const int lane = t & 63;
  const int wq   = t >> 6;             // wave id = col quarter
  const int cl   = lane & 15;          // node-in-tile (A-row select / C col)
  const int kg   = lane >> 4;          // k-group (C rows 4kg..4kg+3)

  // ---- W fragments resident in registers: af[mi][ks] (A row = j) ----
  short8 af[4][4];
#pragma unroll
  for (int mi = 0; mi < 4; ++mi) {
    const int j = 64 * wq + 16 * mi + cl;
#pragma unroll
    for (int ks = 0; ks < 4; ++ks)
      af[mi][ks] = *(const short8*)(Wbf + (size_t)j * HF + 32 * ks + 8 * kg);
  }
  // bias on output rows j = 64wq+16mi+4kg+reg (only j<128 has b1)
  float4 bias4[4];
#pragma unroll
  for (int mi = 0; mi < 4; ++mi) {
    if (wq < 2) bias4[mi] = *(const float4*)(b1 + 64 * wq + 16 * mi + 4 * kg);
    else        bias4[mi] = float4{0.0f, 0.0f, 0.0f, 0.0f};
  }

  // ---- coalesced h staging: slot s=(i*256+t) -> row r=s>>5, chunk c'=s&31;
  //      content = H[r][c' ^ (r&7)]  (inverse-swz source, linear dest) ----
  auto stage = [&](int buf, int tile) {
#pragma unroll
    for (int i = 0; i < 2; ++i) {
      const int s  = i * 256 + t;
      const int rr = s >> 5;
      int node = tile * 16 + rr;
      if (node >= n_nodes) node = n_nodes - 1;
      const int c = (s & 31) ^ (rr & 7);
      gload_lds16(h + (size_t)node * HF + 4 * c,
                  &Hs[buf][(size_t)(i * 256 + (t & 192)) * 4]);
    }
  };

  const int stride = gridDim.x;
  int tile = blockIdx.x;
  int buf  = 0;
  if (tile < n_tiles) stage(0, tile);

  for (; tile < n_tiles; tile += stride) {
    __syncthreads();                   // buf staged; prior reads/stores done
    const int nxt = tile + stride;
    if (nxt < n_tiles) stage(buf ^ 1, nxt);   // lands under this tile's compute

    // ---- B operand: h row (node = tile*16+cl) -> hi/lo bf16 frags ----
    short8 bh[4], bl[4];
#pragma unroll
    for (int ks = 0; ks < 4; ++ks) {
      const int c0 = (8 * ks + 2 * kg)     ^ (cl & 7);
      const int c1 = (8 * ks + 2 * kg + 1) ^ (cl & 7);
      const float4 x = *(const float4*)(&Hs[buf][cl * HF + 4 * c0]);
      const float4 y = *(const float4*)(&Hs[buf][cl * HF + 4 * c1]);
      const float f[8] = {x.x, x.y, x.z, x.w, y.x, y.y, y.z, y.w};
      union { u32 w[4]; short8 v; } H, L;
#pragma unroll
      for (int p = 0; p < 4; ++p) {
        const float a = f[2 * p], b = f[2 * p + 1];
        const u32 hb = cvtpk_bf16(a, b);
        const float ea = a - asf(hb << 16);
        const float eb = b - asf(hb & 0xFFFF0000u);
        H.w[p] = hb;
        L.w[p] = cvtpk_bf16(ea, eb);
      }
      bh[ks] = H.v;
      bl[ks] = L.v;
    }

    // ---- 4 j-tiles: 8 chained MFMA each (W from regs), bias, 8B store ----
    const int nodeR = tile * 16 + cl;
#pragma unroll
    for (int mi = 0; mi < 4; ++mi) {
      f32x4 acc = f32x4{0.0f, 0.0f, 0.0f, 0.0f};
#pragma unroll
      for (int ks = 0; ks < 4; ++ks) {
        acc = __builtin_amdgcn_mfma_f32_16x16x32_bf16(af[mi][ks], bh[ks], acc, 0, 0, 0);
        acc = __builtin_amdgcn_mfma_f32_16x16x32_bf16(af[mi][ks], bl[ks], acc, 0, 0, 0);
      }
      acc[0] += bias4[mi].x; acc[1] += bias4[mi].y;
      acc[2] += bias4[mi].z; acc[3] += bias4[mi].w;
      if (nodeR < n_nodes) {
        uint2 o;
        o.x = (u32)f2h(acc[0]) | ((u32)f2h(acc[1]) << 16);
        o.y = (u32)f2h(acc[2]) | ((u32)f2h(acc[3]) << 16);
        *(uint2*)(&PQ[(size_t)nodeR * 256 + 64 * wq + 16 * mi + 4 * kg]) = o;
      }
    }
    buf ^= 1;
  }
}

// ---------------------------------------------------------------------------
// Kernel B (MFMA): 16 edges per wave-tile.  (unchanged — proven ~44 us)
// ---------------------------------------------------------------------------
__global__ __launch_bounds__(256) void edge_mlp_mfma(
    const u16* __restrict__ PQ, const int* __restrict__ src,
    const int* __restrict__ dst, const float* __restrict__ W2,
    const float* __restrict__ b2, float* __restrict__ out, int n_edges)
{
  const int t    = threadIdx.x;
  const int lane = t & 63;
  const int cl   = lane & 15;
  const int kg   = lane >> 4;

  // B fragments: bf[ks][i] = W2[cl][32ks+8kg+i] (fp16), 0 for cl>=8
  half8 bf[4];
#pragma unroll
  for (int ks = 0; ks < 4; ++ks) {
    if (cl < NTY) {
      const float* wp = W2 + cl * HF + 32 * ks + 8 * kg;
      const float4 x = *(const float4*)wp;
      const float4 y = *(const float4*)(wp + 4);
      bf[ks][0]=(_Float16)x.x; bf[ks][1]=(_Float16)x.y;
      bf[ks][2]=(_Float16)x.z; bf[ks][3]=(_Float16)x.w;
      bf[ks][4]=(_Float16)y.x; bf[ks][5]=(_Float16)y.y;
      bf[ks][6]=(_Float16)y.z; bf[ks][7]=(_Float16)y.w;
    } else {
#pragma unroll
      for (int i = 0; i < 8; ++i) bf[ks][i] = (_Float16)0.0f;
    }
  }
  const float bbias = (cl < NTY) ? b2[cl] : 0.0f;

  const int gw = blockIdx.x * 4 + (t >> 6);   // global wave id
  const int nw = gridDim.x * 4;

  for (int base = gw * 16; base < n_edges; base += nw * 16) {
    int e = base + cl;
    if (e >= n_edges) e = n_edges - 1;
    const int s = src[e];
    const int d = dst[e];
    const u16* pr = PQ + (size_t)s * 256 + 8 * kg;        // P half-row chunk
    const u16* qr = PQ + (size_t)d * 256 + HF + 8 * kg;   // Q half-row chunk

    uint4 P[4], Q[4];
#pragma unroll
    for (int ks = 0; ks < 4; ++ks) P[ks] = *(const uint4*)(pr + 32 * ks);
#pragma unroll
    for (int ks = 0; ks < 4; ++ks) Q[ks] = *(const uint4*)(qr + 32 * ks);

    f32x4 acc = f32x4{0.0f, 0.0f, 0.0f, 0.0f};
#pragma unroll
    for (int ks = 0; ks < 4; ++ks) {
      union { u32 w[4]; half8 v; } a;
      a.w[0] = pk_addrelu_f16(P[ks].x, Q[ks].x);
      a.w[1] = pk_addrelu_f16(P[ks].y, Q[ks].y);
      a.w[2] = pk_addrelu_f16(P[ks].z, Q[ks].z);
      a.w[3] = pk_addrelu_f16(P[ks].w, Q[ks].w);
      acc = __builtin_amdgcn_mfma_f32_16x16x32_f16(a.v, bf[ks], acc, 0, 0, 0);
    }

    // per-reg softmax over the 8 types (lanes cl 0..7; 8..15 are zero-pad)
    float val[4];
#pragma unroll
    for (int r = 0; r < 4; ++r) {
      const float L = acc[r] + bbias;
      float m = fmaxf(L, __shfl_xor(L, 1, 64));
      m = fmaxf(m, __shfl_xor(m, 2, 64));
      m = fmaxf(m, __shfl_xor(m, 4, 64));
      const float ex = __expf(L - m);
      float sm = ex + __shfl_xor(ex, 1, 64);
      sm += __shfl_xor(sm, 2, 64);
      sm += __shfl_xor(sm, 4, 64);
      val[r] = ex / sm;
    }

    if (cl < NTY) {
#pragma unroll
      for (int r = 0; r < 4; ++r) {
        const int ee = base + 4 * kg + r;
        if (ee < n_edges) out[(size_t)ee * NTY + cl] = val[r];
      }
    }
  }
}

// ---------------------------------------------------------------------------
extern "C" void kernel_launch(void* const* d_in, const int* in_sizes, int n_in,
                              void* d_out, int out_size, void* d_ws, size_t ws_size,
                              hipStream_t stream) {
  const float* h   = (const float*)d_in[0];
  const int*   src = (const int*)d_in[1];
  const int*   dst = (const int*)d_in[2];
  const float* W1  = (const float*)d_in[3];
  const float* b1  = (const float*)d_in[4];
  const float* W2  = (const float*)d_in[5];
  const float* b2  = (const float*)d_in[6];
  float* out = (float*)d_out;

  const int n_nodes = in_sizes[0] / HF;   // 50000
  const int n_edges = in_sizes[1];        // 500000
  u16* PQ  = (u16*)d_ws;                  // [n_nodes][256] fp16 = 25.6 MB
  u16* Wbf = PQ + (size_t)n_nodes * 256;  // [256][128] bf16 = 64 KB

  const int n_tiles = (n_nodes + 15) >> 4;          // 3125

  hipLaunchKernelGGL(prep_w, dim3(16), dim3(256), 0, stream, W1, Wbf);
  hipLaunchKernelGGL(node_pq_v4, dim3(512), dim3(256), 0, stream,
                     h, Wbf, b1, PQ, n_nodes, n_tiles);
  hipLaunchKernelGGL(edge_mlp_mfma, dim3(2048), dim3(256), 0, stream,
                     PQ, src, dst, W2, b2, out, n_edges);
}